// Round 1
// baseline (270.580 us; speedup 1.0000x reference)
//
#include <hip/hip_runtime.h>
#include <hip/hip_bf16.h>

// GPT-2 attention block: B=2, S=2048, D=768, H=12, hd=64
#define BATCH 2
#define SEQ   2048
#define DMODEL 768
#define NHEAD 12
#define HDIM  64
#define QKVD  2304   // 3*DMODEL

typedef __bf16 bf16x8 __attribute__((ext_vector_type(8)));
typedef float f32x4 __attribute__((ext_vector_type(4)));

static __device__ inline f32x4 mfma16(bf16x8 a, bf16x8 b, f32x4 c) {
    return __builtin_amdgcn_mfma_f32_16x16x32_bf16(a, b, c, 0, 0, 0);
}

static __device__ inline unsigned short f2bf_bits(float f) {
    __hip_bfloat16 h = __float2bfloat16(f);
    return __builtin_bit_cast(unsigned short, h);
}

// ---------------- conversion kernels ----------------

__global__ __launch_bounds__(256) void f32_to_bf16_k(const float* __restrict__ in,
                                                     __hip_bfloat16* __restrict__ out) {
    int i = blockIdx.x * 256 + threadIdx.x;  // one float4 per thread, exact grid
    float4 v = reinterpret_cast<const float4*>(in)[i];
    ushort4 o;
    o.x = f2bf_bits(v.x); o.y = f2bf_bits(v.y);
    o.z = f2bf_bits(v.z); o.w = f2bf_bits(v.w);
    reinterpret_cast<ushort4*>(out)[i] = o;
}

// in: [R][C] f32 row-major -> out: [C][R] bf16 row-major
__global__ __launch_bounds__(256) void transpose_f32_to_bf16(const float* __restrict__ in,
                                                             __hip_bfloat16* __restrict__ out,
                                                             int R, int C) {
    __shared__ float t[32][33];
    int tx = threadIdx.x & 31, ty = threadIdx.x >> 5;  // 32x8
    int bx = blockIdx.x * 32;  // col base (C)
    int by = blockIdx.y * 32;  // row base (R)
#pragma unroll
    for (int k = 0; k < 4; k++)
        t[ty + k * 8][tx] = in[(size_t)(by + ty + k * 8) * C + bx + tx];
    __syncthreads();
#pragma unroll
    for (int k = 0; k < 4; k++)
        out[(size_t)(bx + ty + k * 8) * R + by + tx] = __float2bfloat16(t[tx][ty + k * 8]);
}

// ---------------- GEMM: C[M][N] = A[M][K] (bf16) @ Bt[N][K]^T (bf16) + bias ----------------
// block = 256 threads = 4 waves in 2x2; each wave owns a 64x64 output tile (4x4 MFMA frags).
// grid = (N/128, M/128). No LDS staging this round (cache-reuse baseline).

template <bool OUT_BF16>
__global__ __launch_bounds__(256) void gemm_bt(const __hip_bfloat16* __restrict__ A,
                                               const __hip_bfloat16* __restrict__ Bt,
                                               const float* __restrict__ bias,
                                               void* __restrict__ Cp,
                                               int M, int N, int K) {
    int tid = threadIdx.x;
    int wid = tid >> 6;
    int lane = tid & 63;
    int lr = lane & 15;   // fragment row/col lane index
    int lg = lane >> 4;   // k-group
    int m0 = blockIdx.y * 128 + (wid >> 1) * 64;
    int n0 = blockIdx.x * 128 + (wid & 1) * 64;

    f32x4 acc[4][4] = {};

    for (int k0 = 0; k0 < K; k0 += 32) {
        bf16x8 af[4], bfr[4];
#pragma unroll
        for (int i = 0; i < 4; i++)
            af[i] = *reinterpret_cast<const bf16x8*>(A + (size_t)(m0 + i * 16 + lr) * K + k0 + lg * 8);
#pragma unroll
        for (int j = 0; j < 4; j++)
            bfr[j] = *reinterpret_cast<const bf16x8*>(Bt + (size_t)(n0 + j * 16 + lr) * K + k0 + lg * 8);
#pragma unroll
        for (int i = 0; i < 4; i++)
#pragma unroll
            for (int j = 0; j < 4; j++)
                acc[i][j] = mfma16(af[i], bfr[j], acc[i][j]);
    }

#pragma unroll
    for (int i = 0; i < 4; i++) {
#pragma unroll
        for (int j = 0; j < 4; j++) {
            int col = n0 + j * 16 + lr;
            float bv = bias[col];
#pragma unroll
            for (int r = 0; r < 4; r++) {
                int row = m0 + i * 16 + lg * 4 + r;  // C/D layout: col=lane&15, row=(lane>>4)*4+reg
                float v = acc[i][j][r] + bv;
                if (OUT_BF16)
                    ((__hip_bfloat16*)Cp)[(size_t)row * N + col] = __float2bfloat16(v);
                else
                    ((float*)Cp)[(size_t)row * N + col] = v;
            }
        }
    }
}

// ---------------- causal flash attention ----------------
// grid = (SEQ/64, BATCH*NHEAD), block = 256 (4 waves). Each wave owns 16 q-rows.
// KV tiles of 32 staged in LDS (padded). Online softmax in fp32.

__global__ __launch_bounds__(256) void flash_attn(const __hip_bfloat16* __restrict__ qkv,
                                                  __hip_bfloat16* __restrict__ attn_out) {
    __shared__ __hip_bfloat16 Kl[32][72];
    __shared__ __hip_bfloat16 Vl[32][72];
    __shared__ __hip_bfloat16 Pl[4][16][40];

    int tid = threadIdx.x;
    int wid = tid >> 6;
    int lane = tid & 63;
    int lr = lane & 15;
    int lg = lane >> 4;

    int qt = blockIdx.x;
    int bh = blockIdx.y;
    int b = bh / NHEAD;
    int h = bh - b * NHEAD;
    int q0 = qt * 64;
    int bbase = b * SEQ;
    int qbase = q0 + wid * 16;

    // Q fragments (A operand, 16 q-rows x hd=64 -> 2 k-steps of 32), kept in regs
    const __hip_bfloat16* qrow = qkv + (size_t)(bbase + qbase + lr) * QKVD + h * HDIM;
    bf16x8 qf[2];
    qf[0] = *reinterpret_cast<const bf16x8*>(qrow + lg * 8);
    qf[1] = *reinterpret_cast<const bf16x8*>(qrow + 32 + lg * 8);

    f32x4 o[4] = {};
    float mrow[4] = {-INFINITY, -INFINITY, -INFINITY, -INFINITY};
    float lrow[4] = {0.f, 0.f, 0.f, 0.f};

    int kv_end = q0 + 64;
    int trow = tid >> 3;
    int tcol = (tid & 7) * 8;

    for (int kv0 = 0; kv0 < kv_end; kv0 += 32) {
        // stage K,V tiles (32 kv-rows x 64 hd) cooperatively: 256 thr x 16B
        const __hip_bfloat16* src = qkv + (size_t)(bbase + kv0 + trow) * QKVD + h * HDIM;
        *reinterpret_cast<uint4*>(&Kl[trow][tcol]) =
            *reinterpret_cast<const uint4*>(src + DMODEL + tcol);
        *reinterpret_cast<uint4*>(&Vl[trow][tcol]) =
            *reinterpret_cast<const uint4*>(src + 2 * DMODEL + tcol);
        __syncthreads();

        if (kv0 <= qbase + 15) {  // wave has at least one unmasked key in this tile
            // S = Q @ K^T  (two 16-col subtiles)
            f32x4 sfr[2];
#pragma unroll
            for (int nt = 0; nt < 2; nt++) {
                f32x4 s = {};
#pragma unroll
                for (int ks = 0; ks < 2; ks++) {
                    bf16x8 kf = *reinterpret_cast<const bf16x8*>(&Kl[nt * 16 + lr][ks * 32 + lg * 8]);
                    s = mfma16(qf[ks], kf, s);
                }
                sfr[nt] = s;
            }
            // scale + causal mask
            const float sc = 0.125f;  // 1/sqrt(64)
#pragma unroll
            for (int nt = 0; nt < 2; nt++) {
                int kvidx = kv0 + nt * 16 + lr;
#pragma unroll
                for (int r = 0; r < 4; r++) {
                    int qr = qbase + lg * 4 + r;
                    float v = sfr[nt][r] * sc;
                    sfr[nt][r] = (kvidx > qr) ? -INFINITY : v;
                }
            }
            // online softmax per q-row (row spread across 16 lanes)
#pragma unroll
            for (int r = 0; r < 4; r++) {
                float mx = fmaxf(sfr[0][r], sfr[1][r]);
#pragma unroll
                for (int off = 1; off < 16; off <<= 1)
                    mx = fmaxf(mx, __shfl_xor(mx, off, 64));
                float mnew = fmaxf(mrow[r], mx);
                float scale_old = __expf(mrow[r] - mnew);
                float p0 = __expf(sfr[0][r] - mnew);
                float p1 = __expf(sfr[1][r] - mnew);
                Pl[wid][lg * 4 + r][lr] = __float2bfloat16(p0);
                Pl[wid][lg * 4 + r][16 + lr] = __float2bfloat16(p1);
                float ps = p0 + p1;
#pragma unroll
                for (int off = 1; off < 16; off <<= 1)
                    ps += __shfl_xor(ps, off, 64);
                lrow[r] = lrow[r] * scale_old + ps;
                mrow[r] = mnew;
#pragma unroll
                for (int c = 0; c < 4; c++) o[c][r] *= scale_old;
            }
            // O += P @ V  (P: 16x32 A-frag via LDS round-trip; V: B-frag scalar reads)
            bf16x8 pf = *reinterpret_cast<const bf16x8*>(&Pl[wid][lr][lg * 8]);
#pragma unroll
            for (int c = 0; c < 4; c++) {
                bf16x8 vf;
#pragma unroll
                for (int i = 0; i < 8; i++)
                    vf[i] = *reinterpret_cast<const __bf16*>(&Vl[lg * 8 + i][c * 16 + lr]);
                o[c] = mfma16(pf, vf, o[c]);
            }
        }
        __syncthreads();
    }

    // epilogue: normalize and store bf16
#pragma unroll
    for (int c = 0; c < 4; c++) {
#pragma unroll
        for (int r = 0; r < 4; r++) {
            int row = qbase + lg * 4 + r;
            float v = o[c][r] / lrow[r];
            attn_out[(size_t)(bbase + row) * DMODEL + h * HDIM + c * 16 + lr] = __float2bfloat16(v);
        }
    }
}

// ---------------- launch ----------------

extern "C" void kernel_launch(void* const* d_in, const int* in_sizes, int n_in,
                              void* d_out, int out_size, void* d_ws, size_t ws_size,
                              hipStream_t stream) {
    const float* hidden = (const float*)d_in[0];   // [2,2048,768]
    const float* w_attn = (const float*)d_in[1];   // [768,2304]
    const float* b_attn = (const float*)d_in[2];   // [2304]
    const float* w_proj = (const float*)d_in[3];   // [768,768]
    const float* b_proj = (const float*)d_in[4];   // [768]
    float* out = (float*)d_out;                    // [2,2048,768]

    char* ws = (char*)d_ws;
    __hip_bfloat16* Xb  = (__hip_bfloat16*)(ws + 0);         // 4096*768*2   = 6291456
    __hip_bfloat16* Wta = (__hip_bfloat16*)(ws + 6291456);   // 2304*768*2   = 3538944
    __hip_bfloat16* Wtp = (__hip_bfloat16*)(ws + 9830400);   // 768*768*2    = 1179648
    __hip_bfloat16* QKV = (__hip_bfloat16*)(ws + 11010048);  // 4096*2304*2  = 18874368
    __hip_bfloat16* AO  = (__hip_bfloat16*)(ws + 29884416);  // 4096*768*2   = 6291456
    // total 36175872 bytes

    const int M = BATCH * SEQ;  // 4096

    // 1) hidden -> bf16
    f32_to_bf16_k<<<dim3(M * DMODEL / (256 * 4)), dim3(256), 0, stream>>>(hidden, Xb);
    // 2) w_attn [768][2304] -> Wta [2304][768] bf16
    transpose_f32_to_bf16<<<dim3(QKVD / 32, DMODEL / 32), dim3(256), 0, stream>>>(w_attn, Wta, DMODEL, QKVD);
    // 3) w_proj [768][768] -> Wtp [768][768] bf16 (transposed)
    transpose_f32_to_bf16<<<dim3(DMODEL / 32, DMODEL / 32), dim3(256), 0, stream>>>(w_proj, Wtp, DMODEL, DMODEL);
    // 4) QKV = Xb @ w_attn + b_attn  -> bf16 [4096][2304]
    gemm_bt<true><<<dim3(QKVD / 128, M / 128), dim3(256), 0, stream>>>(Xb, Wta, b_attn, QKV, M, QKVD, DMODEL);
    // 5) flash attention -> AO bf16 [4096][768]
    flash_attn<<<dim3(SEQ / 64, BATCH * NHEAD), dim3(256), 0, stream>>>(QKV, AO);
    // 6) out = AO @ w_proj + b_proj -> f32
    gemm_bt<false><<<dim3(DMODEL / 128, M / 128), dim3(256), 0, stream>>>(AO, Wtp, b_proj, out, M, DMODEL, DMODEL);
}

// Round 2
// 184.477 us; speedup vs baseline: 1.4667x; 1.4667x over previous
//
#include <hip/hip_runtime.h>
#include <hip/hip_bf16.h>

// GPT-2 attention block: B=2, S=2048, D=768, H=12, hd=64
#define BATCH 2
#define SEQ   2048
#define DMODEL 768
#define NHEAD 12
#define HDIM  64
#define QKVD  2304   // 3*DMODEL

typedef __bf16 bf16x8 __attribute__((ext_vector_type(8)));
typedef float f32x4 __attribute__((ext_vector_type(4)));

static __device__ inline f32x4 mfma16(bf16x8 a, bf16x8 b, f32x4 c) {
    return __builtin_amdgcn_mfma_f32_16x16x32_bf16(a, b, c, 0, 0, 0);
}

static __device__ inline unsigned short f2bf_bits(float f) {
    __hip_bfloat16 h = __float2bfloat16(f);
    return __builtin_bit_cast(unsigned short, h);
}

static __device__ inline unsigned int pack_bf16(float a, float b) {
    return (unsigned int)f2bf_bits(a) | ((unsigned int)f2bf_bits(b) << 16);
}

// ---------------- conversion kernels ----------------

__global__ __launch_bounds__(256) void f32_to_bf16_k(const float* __restrict__ in,
                                                     __hip_bfloat16* __restrict__ out) {
    int i = blockIdx.x * 256 + threadIdx.x;  // one float4 per thread, exact grid
    float4 v = reinterpret_cast<const float4*>(in)[i];
    ushort4 o;
    o.x = f2bf_bits(v.x); o.y = f2bf_bits(v.y);
    o.z = f2bf_bits(v.z); o.w = f2bf_bits(v.w);
    reinterpret_cast<ushort4*>(out)[i] = o;
}

// in: [R][C] f32 row-major -> out: [C][R] bf16 row-major
__global__ __launch_bounds__(256) void transpose_f32_to_bf16(const float* __restrict__ in,
                                                             __hip_bfloat16* __restrict__ out,
                                                             int R, int C) {
    __shared__ float t[32][33];
    int tx = threadIdx.x & 31, ty = threadIdx.x >> 5;  // 32x8
    int bx = blockIdx.x * 32;  // col base (C)
    int by = blockIdx.y * 32;  // row base (R)
#pragma unroll
    for (int k = 0; k < 4; k++)
        t[ty + k * 8][tx] = in[(size_t)(by + ty + k * 8) * C + bx + tx];
    __syncthreads();
#pragma unroll
    for (int k = 0; k < 4; k++)
        out[(size_t)(bx + ty + k * 8) * R + by + tx] = __float2bfloat16(t[tx][ty + k * 8]);
}

// ---------------- GEMM: C[M][N] = A[M][K] (bf16) @ Bt[N][K]^T (bf16) + bias ----------------

template <bool OUT_BF16>
__global__ __launch_bounds__(256) void gemm_bt(const __hip_bfloat16* __restrict__ A,
                                               const __hip_bfloat16* __restrict__ Bt,
                                               const float* __restrict__ bias,
                                               void* __restrict__ Cp,
                                               int M, int N, int K) {
    int tid = threadIdx.x;
    int wid = tid >> 6;
    int lane = tid & 63;
    int lr = lane & 15;
    int lg = lane >> 4;
    int m0 = blockIdx.y * 128 + (wid >> 1) * 64;
    int n0 = blockIdx.x * 128 + (wid & 1) * 64;

    f32x4 acc[4][4] = {};

    for (int k0 = 0; k0 < K; k0 += 32) {
        bf16x8 af[4], bfr[4];
#pragma unroll
        for (int i = 0; i < 4; i++)
            af[i] = *reinterpret_cast<const bf16x8*>(A + (size_t)(m0 + i * 16 + lr) * K + k0 + lg * 8);
#pragma unroll
        for (int j = 0; j < 4; j++)
            bfr[j] = *reinterpret_cast<const bf16x8*>(Bt + (size_t)(n0 + j * 16 + lr) * K + k0 + lg * 8);
#pragma unroll
        for (int i = 0; i < 4; i++)
#pragma unroll
            for (int j = 0; j < 4; j++)
                acc[i][j] = mfma16(af[i], bfr[j], acc[i][j]);
    }

#pragma unroll
    for (int i = 0; i < 4; i++) {
#pragma unroll
        for (int j = 0; j < 4; j++) {
            int col = n0 + j * 16 + lr;
            float bv = bias[col];
#pragma unroll
            for (int r = 0; r < 4; r++) {
                int row = m0 + i * 16 + lg * 4 + r;  // C/D: col=lane&15, row=(lane>>4)*4+reg
                float v = acc[i][j][r] + bv;
                if (OUT_BF16)
                    ((__hip_bfloat16*)Cp)[(size_t)row * N + col] = __float2bfloat16(v);
                else
                    ((float*)Cp)[(size_t)row * N + col] = v;
            }
        }
    }
}

// ---------------- causal flash attention v2 (swapped QK^T, transposed V) ----------------
// grid = (SEQ/64 zigzag, BATCH*NHEAD), block 256 = 4 waves, 16 q-rows/wave, KVBLK=64.
// S^T = mfma(K, Q)  -> per-lane softmax rows (q = lane&15), reduce via 2 shfl_xor.
// O^T = mfma(V^T, P^T): V staged transposed (conflict-free ushort2 writes),
// P packed to LDS as row-major pairs (b32 writes) and read back as b128 B-frags.

__global__ __launch_bounds__(256) void flash_attn(const __hip_bfloat16* __restrict__ qkv,
                                                  __hip_bfloat16* __restrict__ attn_out) {
    __shared__ __hip_bfloat16 Kl[64][72];      // K tile, row-major [kv][d]  (also reused as O staging)
    __shared__ __hip_bfloat16 Vt[64][72];      // V tile transposed [d][kv]
    __shared__ __hip_bfloat16 Pl[4][16][72];   // per-wave P row-major [q][kv]

    int tid = threadIdx.x;
    int wid = tid >> 6;
    int lane = tid & 63;
    int lr = lane & 15;
    int lg = lane >> 4;

    int bx = blockIdx.x;
    int qt = (bx & 1) ? (SEQ / 64 - 1 - (bx >> 1)) : (bx >> 1);  // zigzag for load balance
    int bh = blockIdx.y;
    int b = bh / NHEAD;
    int h = bh - b * NHEAD;
    int q0 = qt * 64;
    int bbase = b * SEQ;
    int qbase = q0 + wid * 16;

    // Q fragment (lane lr = q-row; register image == Q^T B-frag)
    const __hip_bfloat16* qrow = qkv + (size_t)(bbase + qbase + lr) * QKVD + h * HDIM;
    bf16x8 qf0 = *reinterpret_cast<const bf16x8*>(qrow + lg * 8);
    bf16x8 qf1 = *reinterpret_cast<const bf16x8*>(qrow + 32 + lg * 8);

    f32x4 o[4] = {};
    float m = -INFINITY, l = 0.f;

    // staging index maps
    int krow = tid >> 3, kcol = (tid & 7) * 8;     // K: coalesced rows
    int kvp = tid & 31, dgrp = tid >> 5;           // V: conflict-free transposed writes

    for (int kv0 = 0; kv0 <= q0; kv0 += 64) {
        // ---- stage K (row-major) ----
        const __hip_bfloat16* kb = qkv + (size_t)(bbase + kv0) * QKVD + DMODEL + h * HDIM;
        *reinterpret_cast<uint4*>(&Kl[krow][kcol]) =
            *reinterpret_cast<const uint4*>(kb + (size_t)krow * QKVD + kcol);
        *reinterpret_cast<uint4*>(&Kl[krow + 32][kcol]) =
            *reinterpret_cast<const uint4*>(kb + (size_t)(krow + 32) * QKVD + kcol);
        // ---- stage V transposed: thread covers kv rows {2kvp,2kvp+1}, d cols 8dgrp..+7 ----
        const __hip_bfloat16* vb = qkv + (size_t)(bbase + kv0 + 2 * kvp) * QKVD + 2 * DMODEL + h * HDIM + dgrp * 8;
        union { uint4 q; unsigned short s[8]; } va, vb2;
        va.q = *reinterpret_cast<const uint4*>(vb);
        vb2.q = *reinterpret_cast<const uint4*>(vb + QKVD);
#pragma unroll
        for (int i = 0; i < 8; i++)
            *reinterpret_cast<ushort2*>(&Vt[dgrp * 8 + i][2 * kvp]) = make_ushort2(va.s[i], vb2.s[i]);
        __syncthreads();

        int nsub = (kv0 == q0) ? (wid + 1) : 4;  // active 16-kv subtiles (causal)

        // ---- S^T = mfma(K, Q): col=q(lane&15), row=kv((lane>>4)*4+r) ----
        f32x4 st[4];
#pragma unroll
        for (int sub = 0; sub < 4; sub++) {
            if (sub < nsub) {
                bf16x8 kf0 = *reinterpret_cast<const bf16x8*>(&Kl[sub * 16 + lr][lg * 8]);
                bf16x8 kf1 = *reinterpret_cast<const bf16x8*>(&Kl[sub * 16 + lr][32 + lg * 8]);
                f32x4 s = {};
                s = mfma16(kf0, qf0, s);
                s = mfma16(kf1, qf1, s);
                st[sub] = s;
            }
        }

        // ---- scale + causal mask + online softmax (per-lane q = lr) ----
        int q = qbase + lr;
        float mloc = -INFINITY;
#pragma unroll
        for (int sub = 0; sub < 4; sub++) {
            if (sub < nsub) {
#pragma unroll
                for (int r = 0; r < 4; r++) {
                    int kv = kv0 + sub * 16 + lg * 4 + r;
                    float v = st[sub][r] * 0.125f;  // 1/sqrt(64)
                    v = (kv > q) ? -INFINITY : v;
                    st[sub][r] = v;
                    mloc = fmaxf(mloc, v);
                }
            }
        }
        mloc = fmaxf(mloc, __shfl_xor(mloc, 16));
        mloc = fmaxf(mloc, __shfl_xor(mloc, 32));
        float mnew = fmaxf(m, mloc);
        float sc_old = __expf(m - mnew);
        float ls = 0.f;
#pragma unroll
        for (int sub = 0; sub < 4; sub++) {
            if (sub < nsub) {
#pragma unroll
                for (int r = 0; r < 4; r++) {
                    float p = __expf(st[sub][r] - mnew);
                    st[sub][r] = p;
                    ls += p;
                }
            }
        }
        ls += __shfl_xor(ls, 16);
        ls += __shfl_xor(ls, 32);
        l = l * sc_old + ls;
        m = mnew;
#pragma unroll
        for (int c = 0; c < 4; c++) o[c] = o[c] * sc_old;

        // ---- P -> LDS (row-major [q][kv], bf16 pairs as b32 writes) ----
#pragma unroll
        for (int sub = 0; sub < 4; sub++) {
            unsigned int u0 = 0, u1 = 0;
            if (sub < nsub) {
                u0 = pack_bf16(st[sub][0], st[sub][1]);
                u1 = pack_bf16(st[sub][2], st[sub][3]);
            }
            *reinterpret_cast<unsigned int*>(&Pl[wid][lr][sub * 16 + lg * 4]) = u0;
            *reinterpret_cast<unsigned int*>(&Pl[wid][lr][sub * 16 + lg * 4 + 2]) = u1;
        }

        // ---- O^T += mfma(V^T, P^T); same-wave LDS write->read, no barrier needed ----
        int nks = (nsub + 1) >> 1;
#pragma unroll
        for (int ks = 0; ks < 2; ks++) {
            if (ks < nks) {
                bf16x8 pb = *reinterpret_cast<const bf16x8*>(&Pl[wid][lr][ks * 32 + lg * 8]);
#pragma unroll
                for (int c = 0; c < 4; c++) {
                    bf16x8 vf = *reinterpret_cast<const bf16x8*>(&Vt[c * 16 + lr][ks * 32 + lg * 8]);
                    o[c] = mfma16(vf, pb, o[c]);
                }
            }
        }
        __syncthreads();
    }

    // ---- epilogue: O^T -> LDS transpose -> coalesced bf16 stores ----
    float linv = 1.0f / l;
#pragma unroll
    for (int c = 0; c < 4; c++) {
        ushort4 w;
        w.x = f2bf_bits(o[c][0] * linv);
        w.y = f2bf_bits(o[c][1] * linv);
        w.z = f2bf_bits(o[c][2] * linv);
        w.w = f2bf_bits(o[c][3] * linv);
        // O row q = wid*16+lr, d = c*16 + lg*4 + r (4 consecutive d)
        *reinterpret_cast<ushort4*>(&Kl[wid * 16 + lr][c * 16 + lg * 4]) = w;
    }
    __syncthreads();
    int qq = tid >> 2, d0 = (tid & 3) * 16;
    __hip_bfloat16* dst = attn_out + (size_t)(bbase + q0 + qq) * DMODEL + h * HDIM + d0;
    *reinterpret_cast<uint4*>(dst) = *reinterpret_cast<const uint4*>(&Kl[qq][d0]);
    *reinterpret_cast<uint4*>(dst + 8) = *reinterpret_cast<const uint4*>(&Kl[qq][d0 + 8]);
}

// ---------------- launch ----------------

extern "C" void kernel_launch(void* const* d_in, const int* in_sizes, int n_in,
                              void* d_out, int out_size, void* d_ws, size_t ws_size,
                              hipStream_t stream) {
    const float* hidden = (const float*)d_in[0];   // [2,2048,768]
    const float* w_attn = (const float*)d_in[1];   // [768,2304]
    const float* b_attn = (const float*)d_in[2];   // [2304]
    const float* w_proj = (const float*)d_in[3];   // [768,768]
    const float* b_proj = (const float*)d_in[4];   // [768]
    float* out = (float*)d_out;                    // [2,2048,768]

    char* ws = (char*)d_ws;
    __hip_bfloat16* Xb  = (__hip_bfloat16*)(ws + 0);         // 4096*768*2
    __hip_bfloat16* Wta = (__hip_bfloat16*)(ws + 6291456);   // 2304*768*2
    __hip_bfloat16* Wtp = (__hip_bfloat16*)(ws + 9830400);   // 768*768*2
    __hip_bfloat16* QKV = (__hip_bfloat16*)(ws + 11010048);  // 4096*2304*2
    __hip_bfloat16* AO  = (__hip_bfloat16*)(ws + 29884416);  // 4096*768*2

    const int M = BATCH * SEQ;  // 4096

    f32_to_bf16_k<<<dim3(M * DMODEL / (256 * 4)), dim3(256), 0, stream>>>(hidden, Xb);
    transpose_f32_to_bf16<<<dim3(QKVD / 32, DMODEL / 32), dim3(256), 0, stream>>>(w_attn, Wta, DMODEL, QKVD);
    transpose_f32_to_bf16<<<dim3(DMODEL / 32, DMODEL / 32), dim3(256), 0, stream>>>(w_proj, Wtp, DMODEL, DMODEL);
    gemm_bt<true><<<dim3(QKVD / 128, M / 128), dim3(256), 0, stream>>>(Xb, Wta, b_attn, QKV, M, QKVD, DMODEL);
    flash_attn<<<dim3(SEQ / 64, BATCH * NHEAD), dim3(256), 0, stream>>>(QKV, AO);
    gemm_bt<false><<<dim3(DMODEL / 128, M / 128), dim3(256), 0, stream>>>(AO, Wtp, b_proj, out, M, DMODEL, DMODEL);
}

// Round 3
// 139.534 us; speedup vs baseline: 1.9392x; 1.3221x over previous
//
#include <hip/hip_runtime.h>
#include <hip/hip_bf16.h>

// GPT-2 attention block: B=2, S=2048, D=768, H=12, hd=64
#define BATCH 2
#define SEQ   2048
#define DMODEL 768
#define NHEAD 12
#define HDIM  64
#define QKVD  2304   // 3*DMODEL

typedef __bf16 bf16x8 __attribute__((ext_vector_type(8)));
typedef float f32x4 __attribute__((ext_vector_type(4)));

static __device__ inline f32x4 mfma16(bf16x8 a, bf16x8 b, f32x4 c) {
    return __builtin_amdgcn_mfma_f32_16x16x32_bf16(a, b, c, 0, 0, 0);
}

static __device__ inline unsigned short f2bf_bits(float f) {
    __hip_bfloat16 h = __float2bfloat16(f);
    return __builtin_bit_cast(unsigned short, h);
}

static __device__ inline unsigned int pack_bf16(float a, float b) {
    return (unsigned int)f2bf_bits(a) | ((unsigned int)f2bf_bits(b) << 16);
}

// async global->LDS, 16B per lane; lds dst is wave-uniform base (+lane*16 by HW)
static __device__ inline void gload16(const __hip_bfloat16* g, __hip_bfloat16* l) {
    __builtin_amdgcn_global_load_lds(
        (const __attribute__((address_space(1))) void*)g,
        (__attribute__((address_space(3))) void*)l, 16, 0, 0);
}

// ---------------- conversion kernels ----------------

__global__ __launch_bounds__(256) void f32_to_bf16_k(const float* __restrict__ in,
                                                     __hip_bfloat16* __restrict__ out) {
    int i = blockIdx.x * 256 + threadIdx.x;
    float4 v = reinterpret_cast<const float4*>(in)[i];
    ushort4 o;
    o.x = f2bf_bits(v.x); o.y = f2bf_bits(v.y);
    o.z = f2bf_bits(v.z); o.w = f2bf_bits(v.w);
    reinterpret_cast<ushort4*>(out)[i] = o;
}

// in: [R][C] f32 row-major -> out: [C][R] bf16 row-major
__global__ __launch_bounds__(256) void transpose_f32_to_bf16(const float* __restrict__ in,
                                                             __hip_bfloat16* __restrict__ out,
                                                             int R, int C) {
    __shared__ float t[32][33];
    int tx = threadIdx.x & 31, ty = threadIdx.x >> 5;
    int bx = blockIdx.x * 32;
    int by = blockIdx.y * 32;
#pragma unroll
    for (int k = 0; k < 4; k++)
        t[ty + k * 8][tx] = in[(size_t)(by + ty + k * 8) * C + bx + tx];
    __syncthreads();
#pragma unroll
    for (int k = 0; k < 4; k++)
        out[(size_t)(bx + ty + k * 8) * R + by + tx] = __float2bfloat16(t[tx][ty + k * 8]);
}

// ---------------- GEMM (m97 structure): C[M][N] = A[M][K] @ Bt[N][K]^T + bias ----------------
// block 256 = 4 waves (2x2), 128x128 tile, BK=32, LDS staged via global_load_lds w=16.

template <bool OUT_BF16>
__global__ __launch_bounds__(256) void gemm_bt(const __hip_bfloat16* __restrict__ A,
                                               const __hip_bfloat16* __restrict__ Bt,
                                               const float* __restrict__ bias,
                                               void* __restrict__ Cp,
                                               int M, int N, int K) {
    __shared__ __hip_bfloat16 Al[128 * 32];
    __shared__ __hip_bfloat16 Bl[128 * 32];

    int tid = threadIdx.x;
    int wid = tid >> 6;
    int lane = tid & 63;
    int lr = lane & 15;
    int lg = lane >> 4;
    int m0 = blockIdx.y * 128;
    int n0 = blockIdx.x * 128;
    int wm = (wid >> 1) * 64;  // wave m-offset in tile
    int wn = (wid & 1) * 64;   // wave n-offset in tile

    // staging map: lane l of wave w, issue j covers tile row j*64 + w*16 + (l>>2), k-col (l&3)*8
    int srow = wid * 16 + (lane >> 2);
    int scol = (lane & 3) * 8;
    const __hip_bfloat16* ag = A + (size_t)(m0 + srow) * K + scol;
    const __hip_bfloat16* bg = Bt + (size_t)(n0 + srow) * K + scol;
    __hip_bfloat16* al = &Al[wid * 512];
    __hip_bfloat16* bl = &Bl[wid * 512];

    f32x4 acc[4][4] = {};

    for (int k0 = 0; k0 < K; k0 += 32) {
        gload16(ag + k0, al);
        gload16(ag + (size_t)64 * K + k0, al + 2048);
        gload16(bg + k0, bl);
        gload16(bg + (size_t)64 * K + k0, bl + 2048);
        __syncthreads();

        bf16x8 af[4], bfr[4];
#pragma unroll
        for (int i = 0; i < 4; i++)
            af[i] = *reinterpret_cast<const bf16x8*>(&Al[(wm + i * 16 + lr) * 32 + lg * 8]);
#pragma unroll
        for (int j = 0; j < 4; j++)
            bfr[j] = *reinterpret_cast<const bf16x8*>(&Bl[(wn + j * 16 + lr) * 32 + lg * 8]);
#pragma unroll
        for (int i = 0; i < 4; i++)
#pragma unroll
            for (int j = 0; j < 4; j++)
                acc[i][j] = mfma16(af[i], bfr[j], acc[i][j]);
        __syncthreads();
    }

#pragma unroll
    for (int i = 0; i < 4; i++) {
#pragma unroll
        for (int j = 0; j < 4; j++) {
            int col = n0 + wn + j * 16 + lr;
            float bv = bias[col];
#pragma unroll
            for (int r = 0; r < 4; r++) {
                int row = m0 + wm + i * 16 + lg * 4 + r;  // C/D: col=lane&15, row=(lane>>4)*4+reg
                float v = acc[i][j][r] + bv;
                if (OUT_BF16)
                    ((__hip_bfloat16*)Cp)[(size_t)row * N + col] = __float2bfloat16(v);
                else
                    ((float*)Cp)[(size_t)row * N + col] = v;
            }
        }
    }
}

// ---------------- causal flash attention v3 (swapped QK^T, transposed V, prefetch) ----------------
// grid = (SEQ/64 zigzag, BATCH*NHEAD), block 256 = 4 waves, 16 q-rows/wave, KVBLK=64.
// T14 async-stage: next tile's K/V loaded to regs during compute, written to LDS post-barrier.
// LDS stride 80 el (160B): frag-read start banks (8lr+4lg+16ks)%32 -> 2-way (free).

#define LPAD 80

__global__ __launch_bounds__(256) void flash_attn(const __hip_bfloat16* __restrict__ qkv,
                                                  __hip_bfloat16* __restrict__ attn_out) {
    __shared__ __hip_bfloat16 Kl[64][LPAD];      // K tile [kv][d]; reused for O epilogue
    __shared__ __hip_bfloat16 Vt[64][LPAD];      // V tile transposed [d][kv]
    __shared__ __hip_bfloat16 Pl[4][16][LPAD];   // per-wave P [q][kv]

    int tid = threadIdx.x;
    int wid = tid >> 6;
    int lane = tid & 63;
    int lr = lane & 15;
    int lg = lane >> 4;

    int bx = blockIdx.x;
    int qt = (bx & 1) ? (SEQ / 64 - 1 - (bx >> 1)) : (bx >> 1);
    int bh = blockIdx.y;
    int b = bh / NHEAD;
    int h = bh - b * NHEAD;
    int q0 = qt * 64;
    int bbase = b * SEQ;
    int qbase = q0 + wid * 16;

    const __hip_bfloat16* qrow = qkv + (size_t)(bbase + qbase + lr) * QKVD + h * HDIM;
    bf16x8 qf0 = *reinterpret_cast<const bf16x8*>(qrow + lg * 8);
    bf16x8 qf1 = *reinterpret_cast<const bf16x8*>(qrow + 32 + lg * 8);

    f32x4 o[4] = {};
    float m = -INFINITY, l = 0.f;

    int krow = tid >> 3, kcol = (tid & 7) * 8;  // K staging: coalesced rows
    int kvp = tid & 31, dgrp = tid >> 5;        // V staging: transposed pair-writes

    const __hip_bfloat16* kbase = qkv + (size_t)bbase * QKVD + DMODEL + h * HDIM;
    const __hip_bfloat16* vbase = qkv + (size_t)bbase * QKVD + 2 * DMODEL + h * HDIM;

    uint4 rk0, rk1, rva, rvb;
    // prologue: load + write tile 0
    rk0 = *reinterpret_cast<const uint4*>(kbase + (size_t)krow * QKVD + kcol);
    rk1 = *reinterpret_cast<const uint4*>(kbase + (size_t)(krow + 32) * QKVD + kcol);
    rva = *reinterpret_cast<const uint4*>(vbase + (size_t)(2 * kvp) * QKVD + dgrp * 8);
    rvb = *reinterpret_cast<const uint4*>(vbase + (size_t)(2 * kvp + 1) * QKVD + dgrp * 8);
    {
        *reinterpret_cast<uint4*>(&Kl[krow][kcol]) = rk0;
        *reinterpret_cast<uint4*>(&Kl[krow + 32][kcol]) = rk1;
        union { uint4 q; unsigned short s[8]; } ua, ub;
        ua.q = rva; ub.q = rvb;
#pragma unroll
        for (int i = 0; i < 8; i++)
            *reinterpret_cast<ushort2*>(&Vt[dgrp * 8 + i][2 * kvp]) = make_ushort2(ua.s[i], ub.s[i]);
    }
    __syncthreads();

    for (int kv0 = 0; kv0 <= q0; kv0 += 64) {
        bool hn = (kv0 + 64 <= q0);
        if (hn) {  // prefetch next tile into regs (latency hides under compute)
            const __hip_bfloat16* kb = kbase + (size_t)(kv0 + 64) * QKVD;
            const __hip_bfloat16* vb = vbase + (size_t)(kv0 + 64) * QKVD;
            rk0 = *reinterpret_cast<const uint4*>(kb + (size_t)krow * QKVD + kcol);
            rk1 = *reinterpret_cast<const uint4*>(kb + (size_t)(krow + 32) * QKVD + kcol);
            rva = *reinterpret_cast<const uint4*>(vb + (size_t)(2 * kvp) * QKVD + dgrp * 8);
            rvb = *reinterpret_cast<const uint4*>(vb + (size_t)(2 * kvp + 1) * QKVD + dgrp * 8);
        }

        int nsub = (kv0 == q0) ? (wid + 1) : 4;

        // S^T = mfma(K, Q): col=q(lane&15), row=kv((lane>>4)*4+r)
        f32x4 st[4];
#pragma unroll
        for (int sub = 0; sub < 4; sub++) {
            if (sub < nsub) {
                bf16x8 kf0 = *reinterpret_cast<const bf16x8*>(&Kl[sub * 16 + lr][lg * 8]);
                bf16x8 kf1 = *reinterpret_cast<const bf16x8*>(&Kl[sub * 16 + lr][32 + lg * 8]);
                f32x4 s = {};
                s = mfma16(kf0, qf0, s);
                s = mfma16(kf1, qf1, s);
                st[sub] = s;
            }
        }

        // scale + causal mask + online softmax (per-lane q-row = lr)
        int q = qbase + lr;
        float mloc = -INFINITY;
#pragma unroll
        for (int sub = 0; sub < 4; sub++) {
            if (sub < nsub) {
#pragma unroll
                for (int r = 0; r < 4; r++) {
                    int kv = kv0 + sub * 16 + lg * 4 + r;
                    float v = st[sub][r] * 0.125f;
                    v = (kv > q) ? -INFINITY : v;
                    st[sub][r] = v;
                    mloc = fmaxf(mloc, v);
                }
            }
        }
        mloc = fmaxf(mloc, __shfl_xor(mloc, 16));
        mloc = fmaxf(mloc, __shfl_xor(mloc, 32));
        float mnew = fmaxf(m, mloc);
        float sc_old = __expf(m - mnew);
        float ls = 0.f;
#pragma unroll
        for (int sub = 0; sub < 4; sub++) {
            if (sub < nsub) {
#pragma unroll
                for (int r = 0; r < 4; r++) {
                    float p = __expf(st[sub][r] - mnew);
                    st[sub][r] = p;
                    ls += p;
                }
            }
        }
        ls += __shfl_xor(ls, 16);
        ls += __shfl_xor(ls, 32);
        l = l * sc_old + ls;
        m = mnew;
#pragma unroll
        for (int c = 0; c < 4; c++) o[c] = o[c] * sc_old;

        // P -> LDS row-major [q][kv], one b64 write per subtile
#pragma unroll
        for (int sub = 0; sub < 4; sub++) {
            uint2 u = make_uint2(0u, 0u);
            if (sub < nsub) {
                u.x = pack_bf16(st[sub][0], st[sub][1]);
                u.y = pack_bf16(st[sub][2], st[sub][3]);
            }
            *reinterpret_cast<uint2*>(&Pl[wid][lr][sub * 16 + lg * 4]) = u;
        }

        // O^T += mfma(V^T, P^T); same-wave LDS round-trip, no barrier
        int nks = (nsub + 1) >> 1;
#pragma unroll
        for (int ks = 0; ks < 2; ks++) {
            if (ks < nks) {
                bf16x8 pb = *reinterpret_cast<const bf16x8*>(&Pl[wid][lr][ks * 32 + lg * 8]);
#pragma unroll
                for (int c = 0; c < 4; c++) {
                    bf16x8 vf = *reinterpret_cast<const bf16x8*>(&Vt[c * 16 + lr][ks * 32 + lg * 8]);
                    o[c] = mfma16(vf, pb, o[c]);
                }
            }
        }
        __syncthreads();  // all waves done reading K/V LDS

        if (hn) {  // write prefetched tile
            *reinterpret_cast<uint4*>(&Kl[krow][kcol]) = rk0;
            *reinterpret_cast<uint4*>(&Kl[krow + 32][kcol]) = rk1;
            union { uint4 q; unsigned short s[8]; } ua, ub;
            ua.q = rva; ub.q = rvb;
#pragma unroll
            for (int i = 0; i < 8; i++)
                *reinterpret_cast<ushort2*>(&Vt[dgrp * 8 + i][2 * kvp]) = make_ushort2(ua.s[i], ub.s[i]);
        }
        __syncthreads();  // writes visible before next compute
    }

    // epilogue: O^T -> LDS transpose -> coalesced stores
    float linv = 1.0f / l;
#pragma unroll
    for (int c = 0; c < 4; c++) {
        ushort4 w;
        w.x = f2bf_bits(o[c][0] * linv);
        w.y = f2bf_bits(o[c][1] * linv);
        w.z = f2bf_bits(o[c][2] * linv);
        w.w = f2bf_bits(o[c][3] * linv);
        *reinterpret_cast<ushort4*>(&Kl[wid * 16 + lr][c * 16 + lg * 4]) = w;
    }
    __syncthreads();
    int qq = tid >> 2, d0 = (tid & 3) * 16;
    __hip_bfloat16* dst = attn_out + (size_t)(bbase + q0 + qq) * DMODEL + h * HDIM + d0;
    *reinterpret_cast<uint4*>(dst) = *reinterpret_cast<const uint4*>(&Kl[qq][d0]);
    *reinterpret_cast<uint4*>(dst + 8) = *reinterpret_cast<const uint4*>(&Kl[qq][d0 + 8]);
}

// ---------------- launch ----------------

extern "C" void kernel_launch(void* const* d_in, const int* in_sizes, int n_in,
                              void* d_out, int out_size, void* d_ws, size_t ws_size,
                              hipStream_t stream) {
    const float* hidden = (const float*)d_in[0];   // [2,2048,768]
    const float* w_attn = (const float*)d_in[1];   // [768,2304]
    const float* b_attn = (const float*)d_in[2];   // [2304]
    const float* w_proj = (const float*)d_in[3];   // [768,768]
    const float* b_proj = (const float*)d_in[4];   // [768]
    float* out = (float*)d_out;                    // [2,2048,768]

    char* ws = (char*)d_ws;
    __hip_bfloat16* Xb  = (__hip_bfloat16*)(ws + 0);         // 4096*768*2
    __hip_bfloat16* Wta = (__hip_bfloat16*)(ws + 6291456);   // 2304*768*2
    __hip_bfloat16* Wtp = (__hip_bfloat16*)(ws + 9830400);   // 768*768*2
    __hip_bfloat16* QKV = (__hip_bfloat16*)(ws + 11010048);  // 4096*2304*2
    __hip_bfloat16* AO  = (__hip_bfloat16*)(ws + 29884416);  // 4096*768*2

    const int M = BATCH * SEQ;  // 4096

    f32_to_bf16_k<<<dim3(M * DMODEL / (256 * 4)), dim3(256), 0, stream>>>(hidden, Xb);
    transpose_f32_to_bf16<<<dim3(QKVD / 32, DMODEL / 32), dim3(256), 0, stream>>>(w_attn, Wta, DMODEL, QKVD);
    transpose_f32_to_bf16<<<dim3(DMODEL / 32, DMODEL / 32), dim3(256), 0, stream>>>(w_proj, Wtp, DMODEL, DMODEL);
    gemm_bt<true><<<dim3(QKVD / 128, M / 128), dim3(256), 0, stream>>>(Xb, Wta, b_attn, QKV, M, QKVD, DMODEL);
    flash_attn<<<dim3(SEQ / 64, BATCH * NHEAD), dim3(256), 0, stream>>>(QKV, AO);
    gemm_bt<false><<<dim3(DMODEL / 128, M / 128), dim3(256), 0, stream>>>(AO, Wtp, b_proj, out, M, DMODEL, DMODEL);
}

// Round 4
// 132.667 us; speedup vs baseline: 2.0395x; 1.0518x over previous
//
#include <hip/hip_runtime.h>
#include <hip/hip_bf16.h>

// GPT-2 attention block: B=2, S=2048, D=768, H=12, hd=64
#define BATCH 2
#define SEQ   2048
#define DMODEL 768
#define NHEAD 12
#define HDIM  64
#define QKVD  2304   // 3*DMODEL

typedef __bf16 bf16x8 __attribute__((ext_vector_type(8)));
typedef float f32x4 __attribute__((ext_vector_type(4)));
typedef float f32x16 __attribute__((ext_vector_type(16)));

static __device__ inline f32x4 mfma16(bf16x8 a, bf16x8 b, f32x4 c) {
    return __builtin_amdgcn_mfma_f32_16x16x32_bf16(a, b, c, 0, 0, 0);
}
static __device__ inline f32x16 mfma32(bf16x8 a, bf16x8 b, f32x16 c) {
    return __builtin_amdgcn_mfma_f32_32x32x16_bf16(a, b, c, 0, 0, 0);
}

static __device__ inline unsigned short f2bf_bits(float f) {
    __hip_bfloat16 h = __float2bfloat16(f);
    return __builtin_bit_cast(unsigned short, h);
}
static __device__ inline unsigned int pack_bf16(float a, float b) {
    return (unsigned int)f2bf_bits(a) | ((unsigned int)f2bf_bits(b) << 16);
}

// async global->LDS, 16B per lane
static __device__ inline void gload16(const __hip_bfloat16* g, __hip_bfloat16* l) {
    __builtin_amdgcn_global_load_lds(
        (const __attribute__((address_space(1))) void*)g,
        (__attribute__((address_space(3))) void*)l, 16, 0, 0);
}

// ---------------- conversion kernels ----------------

__global__ __launch_bounds__(256) void f32_to_bf16_k(const float* __restrict__ in,
                                                     __hip_bfloat16* __restrict__ out) {
    int i = blockIdx.x * 256 + threadIdx.x;
    float4 v = reinterpret_cast<const float4*>(in)[i];
    ushort4 o;
    o.x = f2bf_bits(v.x); o.y = f2bf_bits(v.y);
    o.z = f2bf_bits(v.z); o.w = f2bf_bits(v.w);
    reinterpret_cast<ushort4*>(out)[i] = o;
}

__global__ __launch_bounds__(256) void transpose_f32_to_bf16(const float* __restrict__ in,
                                                             __hip_bfloat16* __restrict__ out,
                                                             int R, int C) {
    __shared__ float t[32][33];
    int tx = threadIdx.x & 31, ty = threadIdx.x >> 5;
    int bx = blockIdx.x * 32;
    int by = blockIdx.y * 32;
#pragma unroll
    for (int k = 0; k < 4; k++)
        t[ty + k * 8][tx] = in[(size_t)(by + ty + k * 8) * C + bx + tx];
    __syncthreads();
#pragma unroll
    for (int k = 0; k < 4; k++)
        out[(size_t)(bx + ty + k * 8) * R + by + tx] = __float2bfloat16(t[tx][ty + k * 8]);
}

// ---------------- GEMM (m97 structure, unchanged) ----------------

template <bool OUT_BF16>
__global__ __launch_bounds__(256) void gemm_bt(const __hip_bfloat16* __restrict__ A,
                                               const __hip_bfloat16* __restrict__ Bt,
                                               const float* __restrict__ bias,
                                               void* __restrict__ Cp,
                                               int M, int N, int K) {
    __shared__ __hip_bfloat16 Al[128 * 32];
    __shared__ __hip_bfloat16 Bl[128 * 32];

    int tid = threadIdx.x;
    int wid = tid >> 6;
    int lane = tid & 63;
    int lr = lane & 15;
    int lg = lane >> 4;
    int m0 = blockIdx.y * 128;
    int n0 = blockIdx.x * 128;
    int wm = (wid >> 1) * 64;
    int wn = (wid & 1) * 64;

    int srow = wid * 16 + (lane >> 2);
    int scol = (lane & 3) * 8;
    const __hip_bfloat16* ag = A + (size_t)(m0 + srow) * K + scol;
    const __hip_bfloat16* bg = Bt + (size_t)(n0 + srow) * K + scol;
    __hip_bfloat16* al = &Al[wid * 512];
    __hip_bfloat16* bl = &Bl[wid * 512];

    f32x4 acc[4][4] = {};

    for (int k0 = 0; k0 < K; k0 += 32) {
        gload16(ag + k0, al);
        gload16(ag + (size_t)64 * K + k0, al + 2048);
        gload16(bg + k0, bl);
        gload16(bg + (size_t)64 * K + k0, bl + 2048);
        __syncthreads();

        bf16x8 af[4], bfr[4];
#pragma unroll
        for (int i = 0; i < 4; i++)
            af[i] = *reinterpret_cast<const bf16x8*>(&Al[(wm + i * 16 + lr) * 32 + lg * 8]);
#pragma unroll
        for (int j = 0; j < 4; j++)
            bfr[j] = *reinterpret_cast<const bf16x8*>(&Bl[(wn + j * 16 + lr) * 32 + lg * 8]);
#pragma unroll
        for (int i = 0; i < 4; i++)
#pragma unroll
            for (int j = 0; j < 4; j++)
                acc[i][j] = mfma16(af[i], bfr[j], acc[i][j]);
        __syncthreads();
    }

#pragma unroll
    for (int i = 0; i < 4; i++) {
#pragma unroll
        for (int j = 0; j < 4; j++) {
            int col = n0 + wn + j * 16 + lr;
            float bv = bias[col];
#pragma unroll
            for (int r = 0; r < 4; r++) {
                int row = m0 + wm + i * 16 + lg * 4 + r;
                float v = acc[i][j][r] + bv;
                if (OUT_BF16)
                    ((__hip_bfloat16*)Cp)[(size_t)row * N + col] = __float2bfloat16(v);
                else
                    ((float*)Cp)[(size_t)row * N + col] = v;
            }
        }
    }
}

// ---------------- causal flash attention v4: 32x32 MFMA + wave-pair kv-split ----------------
// grid (SEQ/64 zigzag, B*H), block 256 = 4 waves. Wave w: q-half qh=w>>1 (32 q-rows,
// lane&31 = q), kv-subtile parity sw=w&1 (owns kv [sw*32, sw*32+32) of each 64-tile).
// S^T = mfma32(K, Q) -> per-lane softmax (16 local + 1 shfl32). O^T = mfma32(V^T, P^T).
// All LDS tiles XOR-chunk-swizzled (write & read use same involution). End: flash-combine
// of wave-pair partials (m,l,O) via LDS. Diagonal tile is the only masked iteration.

#define KS2 0.18033688f  // 0.125 * log2(e)

__global__ __launch_bounds__(256) void flash_attn(const __hip_bfloat16* __restrict__ qkv,
                                                  __hip_bfloat16* __restrict__ attn_out) {
    __shared__ __align__(16) char smem[8192 + 8192 + 9216 + 512];
    __hip_bfloat16* KL = (__hip_bfloat16*)smem;            // [64][64] swizzled (row, d-chunk^row&7)
    __hip_bfloat16* VT = (__hip_bfloat16*)(smem + 8192);   // [64][64] V^T swizzled (d, kv-chunk^d&7)
    __hip_bfloat16* PL = (__hip_bfloat16*)(smem + 16384);  // [4][32*32] per-wave P
    __hip_bfloat16* OL = (__hip_bfloat16*)(smem + 16384);  // [64][72] epilogue staging (aliases PL)
    float* SC = (float*)smem;                              // [2][64*32] combine O-partials (aliases KL+VT)
    float* ML = (float*)(smem + 8192 + 8192 + 9216);       // [2][2][32] combine m,l

    int tid = threadIdx.x;
    int w = tid >> 6;
    int lane = tid & 63;
    int l31 = lane & 31;
    int lg2 = lane >> 5;
    int qh = w >> 1;   // q-half
    int sw = w & 1;    // kv-subtile parity

    int bx = blockIdx.x;
    int qt = (bx & 1) ? (SEQ / 64 - 1 - (bx >> 1)) : (bx >> 1);  // zigzag
    int bh = blockIdx.y;
    int b = bh / NHEAD;
    int h = bh - b * NHEAD;
    int q0 = qt * 64;
    int bbase = b * SEQ;
    int qrow = q0 + qh * 32 + l31;   // this lane's q row

    const __hip_bfloat16* kbase = qkv + (size_t)bbase * QKVD + DMODEL + h * HDIM;
    const __hip_bfloat16* vbase = qkv + (size_t)bbase * QKVD + 2 * DMODEL + h * HDIM;

    // Q fragments (B operand: lane&31 = q col, k = d = kd*16 + lg2*8 + i)
    const __hip_bfloat16* qg = qkv + (size_t)(bbase + qrow) * QKVD + h * HDIM;
    bf16x8 qf[4];
#pragma unroll
    for (int kd = 0; kd < 4; kd++)
        qf[kd] = *reinterpret_cast<const bf16x8*>(qg + kd * 16 + lg2 * 8);

    f32x16 o0 = {}, o1 = {};
    float m = -3.0e38f, l = 0.f;

    // staging maps
    int krow = tid >> 2, kq = tid & 3;                  // K: row, d-quarter
    int va = (tid >> 2) & 15;                           // V: kv-quad
    int vb = (tid & 3) | (w << 2);                      // V: d-quad
    union U2 { uint2 u; unsigned short s[4]; };

    uint4 rk0, rk1;
    U2 rv[4];

    // prologue: load tile 0
    {
        const __hip_bfloat16* kg = kbase + (size_t)krow * QKVD + kq * 16;
        rk0 = *reinterpret_cast<const uint4*>(kg);
        rk1 = *reinterpret_cast<const uint4*>(kg + 8);
        const __hip_bfloat16* vg = vbase + (size_t)(4 * va) * QKVD + vb * 4;
#pragma unroll
        for (int j = 0; j < 4; j++)
            rv[j].u = *reinterpret_cast<const uint2*>(vg + (size_t)j * QKVD);
    }
    // write tile 0
    {
        *reinterpret_cast<uint4*>(&KL[krow * 64 + (((2 * kq) ^ (krow & 7)) << 3)]) = rk0;
        *reinterpret_cast<uint4*>(&KL[krow * 64 + (((2 * kq + 1) ^ (krow & 7)) << 3)]) = rk1;
#pragma unroll
        for (int i = 0; i < 4; i++) {
            int d = 4 * vb + i;
            ushort4 w4 = make_ushort4(rv[0].s[i], rv[1].s[i], rv[2].s[i], rv[3].s[i]);
            *reinterpret_cast<ushort4*>(&VT[d * 64 + (((va >> 1) ^ (d & 7)) << 3) + ((va & 1) << 2)]) = w4;
        }
    }
    __syncthreads();

    int T = qt + 1;
    for (int t = 0; t < T; t++) {
        bool hn = (t + 1 < T);
        if (hn) {  // T14: prefetch next tile into regs
            int kv0n = (t + 1) * 64;
            const __hip_bfloat16* kg = kbase + (size_t)(kv0n + krow) * QKVD + kq * 16;
            rk0 = *reinterpret_cast<const uint4*>(kg);
            rk1 = *reinterpret_cast<const uint4*>(kg + 8);
            const __hip_bfloat16* vg = vbase + (size_t)(kv0n + 4 * va) * QKVD + vb * 4;
#pragma unroll
            for (int j = 0; j < 4; j++)
                rv[j].u = *reinterpret_cast<const uint2*>(vg + (size_t)j * QKVD);
        }

        bool diag = (t == qt);
        bool active = !(diag && sw > qh);

        if (active) {
            // ---- S^T = mfma32(K, Q): col = q (lane&31), rows = kv ----
            int kr = sw * 32 + l31;
            f32x16 st = {};
#pragma unroll
            for (int kd = 0; kd < 4; kd++) {
                bf16x8 kf = *reinterpret_cast<const bf16x8*>(
                    &KL[kr * 64 + (((2 * kd + lg2) ^ (l31 & 7)) << 3)]);
                st = mfma32(kf, qf[kd], st);
            }
            // mask only the diagonal subtile
            if (diag && sw == qh) {
#pragma unroll
                for (int j = 0; j < 16; j++) {
                    int kvloc = (j & 3) + 8 * (j >> 2) + 4 * lg2;
                    if (kvloc > l31) st[j] = -3.0e38f;
                }
            }
            // ---- online softmax (raw scores; 1/8 folded into exp2 constant) ----
            float tm[16];
#pragma unroll
            for (int j = 0; j < 16; j++) tm[j] = st[j];
#pragma unroll
            for (int dd = 8; dd >= 1; dd >>= 1)
#pragma unroll
                for (int j = 0; j < 8; j++)
                    if (j < dd) tm[j] = fmaxf(tm[j], tm[j + dd]);
            float mx = fmaxf(tm[0], __shfl_xor(tm[0], 32, 64));
            float mnew = fmaxf(m, mx);
            float sc = __builtin_amdgcn_exp2f((m - mnew) * KS2);
#pragma unroll
            for (int j = 0; j < 16; j++)
                st[j] = __builtin_amdgcn_exp2f((st[j] - mnew) * KS2);
            float ts[16];
#pragma unroll
            for (int j = 0; j < 16; j++) ts[j] = st[j];
#pragma unroll
            for (int dd = 8; dd >= 1; dd >>= 1)
#pragma unroll
                for (int j = 0; j < 8; j++)
                    if (j < dd) ts[j] += ts[j + dd];
            float ls = ts[0] + __shfl_xor(ts[0], 32, 64);
            l = l * sc + ls;
            m = mnew;
            o0 *= sc;
            o1 *= sc;

            // ---- P -> LDS (row q = lane&31, 32 kv; chunk-swizzled) ----
            __hip_bfloat16* PLw = PL + w * 1024;
#pragma unroll
            for (int g = 0; g < 4; g++) {
                uint2 u;
                u.x = pack_bf16(st[4 * g + 0], st[4 * g + 1]);
                u.y = pack_bf16(st[4 * g + 2], st[4 * g + 3]);
                *reinterpret_cast<uint2*>(
                    &PLw[l31 * 32 + ((g ^ (l31 & 3)) << 3) + (lg2 << 2)]) = u;
            }
            // ---- O^T += mfma32(V^T, P^T); same-wave LDS round-trip ----
#pragma unroll
            for (int kd2 = 0; kd2 < 2; kd2++) {
                bf16x8 pf = *reinterpret_cast<const bf16x8*>(
                    &PLw[l31 * 32 + (((2 * kd2 + lg2) ^ (l31 & 3)) << 3)]);
                {
                    int dr = l31;
                    bf16x8 vf = *reinterpret_cast<const bf16x8*>(
                        &VT[dr * 64 + (((4 * sw + 2 * kd2 + lg2) ^ (l31 & 7)) << 3)]);
                    o0 = mfma32(vf, pf, o0);
                }
                {
                    int dr = 32 + l31;
                    bf16x8 vf = *reinterpret_cast<const bf16x8*>(
                        &VT[dr * 64 + (((4 * sw + 2 * kd2 + lg2) ^ (l31 & 7)) << 3)]);
                    o1 = mfma32(vf, pf, o1);
                }
            }
        }
        __syncthreads();  // all waves done reading KL/VT
        if (hn) {
            *reinterpret_cast<uint4*>(&KL[krow * 64 + (((2 * kq) ^ (krow & 7)) << 3)]) = rk0;
            *reinterpret_cast<uint4*>(&KL[krow * 64 + (((2 * kq + 1) ^ (krow & 7)) << 3)]) = rk1;
#pragma unroll
            for (int i = 0; i < 4; i++) {
                int d = 4 * vb + i;
                ushort4 w4 = make_ushort4(rv[0].s[i], rv[1].s[i], rv[2].s[i], rv[3].s[i]);
                *reinterpret_cast<ushort4*>(&VT[d * 64 + (((va >> 1) ^ (d & 7)) << 3) + ((va & 1) << 2)]) = w4;
            }
        }
        __syncthreads();  // next tile visible
    }

    // ---- combine wave-pair partials ----
    if (sw == 1) {
#pragma unroll
        for (int j = 0; j < 16; j++) {
            int dl = (j & 3) + 8 * (j >> 2) + 4 * lg2;
            SC[qh * 2048 + dl * 32 + l31] = o0[j];
            SC[qh * 2048 + (32 + dl) * 32 + l31] = o1[j];
        }
        if (lg2 == 0) {
            ML[(qh * 2 + 0) * 32 + l31] = m;
            ML[(qh * 2 + 1) * 32 + l31] = l;
        }
    }
    __syncthreads();
    if (sw == 0) {
        float mb = ML[(qh * 2 + 0) * 32 + l31];
        float lb = ML[(qh * 2 + 1) * 32 + l31];
        float M = fmaxf(m, mb);
        float ea = __builtin_amdgcn_exp2f((m - M) * KS2);
        float eb = __builtin_amdgcn_exp2f((mb - M) * KS2);
        float L = l * ea + lb * eb;
        float linv = 1.0f / L;
        int row = qh * 32 + l31;
#pragma unroll
        for (int od = 0; od < 2; od++) {
#pragma unroll
            for (int g = 0; g < 4; g++) {
                int dbase = od * 32 + 8 * g + 4 * lg2;
                ushort4 w4;
                float v0 = (od ? o1[4 * g + 0] : o0[4 * g + 0]) * ea + SC[qh * 2048 + (dbase + 0) * 32 + l31] * eb;
                float v1 = (od ? o1[4 * g + 1] : o0[4 * g + 1]) * ea + SC[qh * 2048 + (dbase + 1) * 32 + l31] * eb;
                float v2 = (od ? o1[4 * g + 2] : o0[4 * g + 2]) * ea + SC[qh * 2048 + (dbase + 2) * 32 + l31] * eb;
                float v3 = (od ? o1[4 * g + 3] : o0[4 * g + 3]) * ea + SC[qh * 2048 + (dbase + 3) * 32 + l31] * eb;
                w4.x = f2bf_bits(v0 * linv);
                w4.y = f2bf_bits(v1 * linv);
                w4.z = f2bf_bits(v2 * linv);
                w4.w = f2bf_bits(v3 * linv);
                *reinterpret_cast<ushort4*>(&OL[row * 72 + dbase]) = w4;
            }
        }
    }
    __syncthreads();
    // coalesced store
    {
        int row = tid >> 2, q4 = tid & 3;
        __hip_bfloat16* dst = attn_out + (size_t)(bbase + q0 + row) * DMODEL + h * HDIM + q4 * 16;
        *reinterpret_cast<uint4*>(dst) = *reinterpret_cast<const uint4*>(&OL[row * 72 + q4 * 16]);
        *reinterpret_cast<uint4*>(dst + 8) = *reinterpret_cast<const uint4*>(&OL[row * 72 + q4 * 16 + 8]);
    }
}

// ---------------- launch ----------------

extern "C" void kernel_launch(void* const* d_in, const int* in_sizes, int n_in,
                              void* d_out, int out_size, void* d_ws, size_t ws_size,
                              hipStream_t stream) {
    const float* hidden = (const float*)d_in[0];   // [2,2048,768]
    const float* w_attn = (const float*)d_in[1];   // [768,2304]
    const float* b_attn = (const float*)d_in[2];   // [2304]
    const float* w_proj = (const float*)d_in[3];   // [768,768]
    const float* b_proj = (const float*)d_in[4];   // [768]
    float* out = (float*)d_out;                    // [2,2048,768]

    char* ws = (char*)d_ws;
    __hip_bfloat16* Xb  = (__hip_bfloat16*)(ws + 0);         // 4096*768*2
    __hip_bfloat16* Wta = (__hip_bfloat16*)(ws + 6291456);   // 2304*768*2
    __hip_bfloat16* Wtp = (__hip_bfloat16*)(ws + 9830400);   // 768*768*2
    __hip_bfloat16* QKV = (__hip_bfloat16*)(ws + 11010048);  // 4096*2304*2
    __hip_bfloat16* AO  = (__hip_bfloat16*)(ws + 29884416);  // 4096*768*2

    const int M = BATCH * SEQ;  // 4096

    f32_to_bf16_k<<<dim3(M * DMODEL / (256 * 4)), dim3(256), 0, stream>>>(hidden, Xb);
    transpose_f32_to_bf16<<<dim3(QKVD / 32, DMODEL / 32), dim3(256), 0, stream>>>(w_attn, Wta, DMODEL, QKVD);
    transpose_f32_to_bf16<<<dim3(DMODEL / 32, DMODEL / 32), dim3(256), 0, stream>>>(w_proj, Wtp, DMODEL, DMODEL);
    gemm_bt<true><<<dim3(QKVD / 128, M / 128), dim3(256), 0, stream>>>(Xb, Wta, b_attn, QKV, M, QKVD, DMODEL);
    flash_attn<<<dim3(SEQ / 64, BATCH * NHEAD), dim3(256), 0, stream>>>(QKV, AO);
    gemm_bt<false><<<dim3(DMODEL / 128, M / 128), dim3(256), 0, stream>>>(AO, Wtp, b_proj, out, M, DMODEL, DMODEL);
}

// Round 5
// 128.273 us; speedup vs baseline: 2.1094x; 1.0343x over previous
//
#include <hip/hip_runtime.h>
#include <hip/hip_bf16.h>

// GPT-2 attention block: B=2, S=2048, D=768, H=12, hd=64
#define BATCH 2
#define SEQ   2048
#define DMODEL 768
#define NHEAD 12
#define HDIM  64
#define QKVD  2304   // 3*DMODEL

typedef __bf16 bf16x8 __attribute__((ext_vector_type(8)));
typedef float f32x4 __attribute__((ext_vector_type(4)));
typedef float f32x16 __attribute__((ext_vector_type(16)));

static __device__ inline f32x4 mfma16(bf16x8 a, bf16x8 b, f32x4 c) {
    return __builtin_amdgcn_mfma_f32_16x16x32_bf16(a, b, c, 0, 0, 0);
}
static __device__ inline f32x16 mfma32(bf16x8 a, bf16x8 b, f32x16 c) {
    return __builtin_amdgcn_mfma_f32_32x32x16_bf16(a, b, c, 0, 0, 0);
}

static __device__ inline unsigned short f2bf_bits(float f) {
    __hip_bfloat16 h = __float2bfloat16(f);
    return __builtin_bit_cast(unsigned short, h);
}
static __device__ inline unsigned int pack_bf16(float a, float b) {
    return (unsigned int)f2bf_bits(a) | ((unsigned int)f2bf_bits(b) << 16);
}

// async global->LDS, 16B per lane
static __device__ inline void gload16(const __hip_bfloat16* g, __hip_bfloat16* l) {
    __builtin_amdgcn_global_load_lds(
        (const __attribute__((address_space(1))) void*)g,
        (__attribute__((address_space(3))) void*)l, 16, 0, 0);
}

// ---------------- conversion kernels ----------------

__global__ __launch_bounds__(256) void f32_to_bf16_k(const float* __restrict__ in,
                                                     __hip_bfloat16* __restrict__ out) {
    int i = blockIdx.x * 256 + threadIdx.x;
    float4 v = reinterpret_cast<const float4*>(in)[i];
    ushort4 o;
    o.x = f2bf_bits(v.x); o.y = f2bf_bits(v.y);
    o.z = f2bf_bits(v.z); o.w = f2bf_bits(v.w);
    reinterpret_cast<ushort4*>(out)[i] = o;
}

__global__ __launch_bounds__(256) void transpose_f32_to_bf16(const float* __restrict__ in,
                                                             __hip_bfloat16* __restrict__ out,
                                                             int R, int C) {
    __shared__ float t[32][33];
    int tx = threadIdx.x & 31, ty = threadIdx.x >> 5;
    int bx = blockIdx.x * 32;
    int by = blockIdx.y * 32;
#pragma unroll
    for (int k = 0; k < 4; k++)
        t[ty + k * 8][tx] = in[(size_t)(by + ty + k * 8) * C + bx + tx];
    __syncthreads();
#pragma unroll
    for (int k = 0; k < 4; k++)
        out[(size_t)(bx + ty + k * 8) * R + by + tx] = __float2bfloat16(t[tx][ty + k * 8]);
}

// ---------------- GEMM (m97 structure, unchanged) ----------------

template <bool OUT_BF16>
__global__ __launch_bounds__(256) void gemm_bt(const __hip_bfloat16* __restrict__ A,
                                               const __hip_bfloat16* __restrict__ Bt,
                                               const float* __restrict__ bias,
                                               void* __restrict__ Cp,
                                               int M, int N, int K) {
    __shared__ __hip_bfloat16 Al[128 * 32];
    __shared__ __hip_bfloat16 Bl[128 * 32];

    int tid = threadIdx.x;
    int wid = tid >> 6;
    int lane = tid & 63;
    int lr = lane & 15;
    int lg = lane >> 4;
    int m0 = blockIdx.y * 128;
    int n0 = blockIdx.x * 128;
    int wm = (wid >> 1) * 64;
    int wn = (wid & 1) * 64;

    int srow = wid * 16 + (lane >> 2);
    int scol = (lane & 3) * 8;
    const __hip_bfloat16* ag = A + (size_t)(m0 + srow) * K + scol;
    const __hip_bfloat16* bg = Bt + (size_t)(n0 + srow) * K + scol;
    __hip_bfloat16* al = &Al[wid * 512];
    __hip_bfloat16* bl = &Bl[wid * 512];

    f32x4 acc[4][4] = {};

    for (int k0 = 0; k0 < K; k0 += 32) {
        gload16(ag + k0, al);
        gload16(ag + (size_t)64 * K + k0, al + 2048);
        gload16(bg + k0, bl);
        gload16(bg + (size_t)64 * K + k0, bl + 2048);
        __syncthreads();

        bf16x8 af[4], bfr[4];
#pragma unroll
        for (int i = 0; i < 4; i++)
            af[i] = *reinterpret_cast<const bf16x8*>(&Al[(wm + i * 16 + lr) * 32 + lg * 8]);
#pragma unroll
        for (int j = 0; j < 4; j++)
            bfr[j] = *reinterpret_cast<const bf16x8*>(&Bl[(wn + j * 16 + lr) * 32 + lg * 8]);
#pragma unroll
        for (int i = 0; i < 4; i++)
#pragma unroll
            for (int j = 0; j < 4; j++)
                acc[i][j] = mfma16(af[i], bfr[j], acc[i][j]);
        __syncthreads();
    }

#pragma unroll
    for (int i = 0; i < 4; i++) {
#pragma unroll
        for (int j = 0; j < 4; j++) {
            int col = n0 + wn + j * 16 + lr;
            float bv = bias[col];
#pragma unroll
            for (int r = 0; r < 4; r++) {
                int row = m0 + wm + i * 16 + lg * 4 + r;
                float v = acc[i][j][r] + bv;
                if (OUT_BF16)
                    ((__hip_bfloat16*)Cp)[(size_t)row * N + col] = __float2bfloat16(v);
                else
                    ((float*)Cp)[(size_t)row * N + col] = v;
            }
        }
    }
}

// ---------------- causal flash attention v5: high-occupancy 2-wave blocks ----------------
// 1536 blocks x 128 thr. Block = 32 q-rows; wave w = kv parity (owns [64t+32w, +32) of
// each 64-kv tile). K frags reg-prefetched from global (L2-resident). P repacked fully
// in-register (pack_bf16 + shfl_xor(32)). Only V^T staged in LDS (chunk-XOR swizzle,
// double-buffered, 1 barrier/iter). Wave-pair (m,l,O^T) combine at end via LDS.
// Dispatch: XCD gets 3 heads (KV fits its L2); largest q-tiles dispatched first.

#define KS2 0.18033688f  // 0.125 * log2(e)

__global__ __launch_bounds__(128, 3) void flash_attn(const __hip_bfloat16* __restrict__ qkv,
                                                     __hip_bfloat16* __restrict__ attn_out) {
    __shared__ __align__(16) char smem[16640];
    __hip_bfloat16* VT = (__hip_bfloat16*)smem;            // [2][64 d][64 kv] swizzled
    float* SC = (float*)smem;                              // [64 d][32 q] combine (aliases VT, post-loop)
    __hip_bfloat16* OL = (__hip_bfloat16*)(smem + 8192);   // [32 q][72] epilogue staging
    float* ML = (float*)(smem + 16384);                    // [64] m,l of wave 1

    int tid = threadIdx.x;
    int w = tid >> 6;        // wave = kv parity
    int lane = tid & 63;
    int l31 = lane & 31;
    int lg2 = lane >> 5;

    // block -> (xcd-chunked head, descending q-tile)
    int wg = blockIdx.x;
    int xcd = wg & 7;
    int slot = wg >> 3;          // 0..191
    int hsl = slot % 3;
    int qsl = slot / 3;          // 0..63
    int bh = xcd * 3 + hsl;
    int it = 63 - qsl;           // largest first
    int b = bh / NHEAD;
    int h = bh - b * NHEAD;
    int q0 = it * 32;
    int T = (it + 2) >> 1;       // 64-kv tiles covering [0, q0+32)
    int bbase = b * SEQ;

    const __hip_bfloat16* Kg = qkv + (size_t)bbase * QKVD + DMODEL + h * HDIM;
    const __hip_bfloat16* Vg = qkv + (size_t)bbase * QKVD + 2 * DMODEL + h * HDIM;

    // Q fragments (B operand: col=q=l31, k=d)
    const __hip_bfloat16* qg = qkv + (size_t)(bbase + q0 + l31) * QKVD + h * HDIM;
    bf16x8 qf[4];
#pragma unroll
    for (int kd = 0; kd < 4; kd++)
        qf[kd] = *reinterpret_cast<const bf16x8*>(qg + kd * 16 + lg2 * 8);

    f32x16 o0 = {}, o1 = {};
    float m = -3.0e38f, l = 0.f;

    // V staging map: thread (kvp=tid&31, dgrp=tid>>5): kv rows {2kvp,2kvp+1}, d cols 16dgrp..+15
    int kvp = tid & 31;
    int dgrp = tid >> 5;
    // K frag rows for this wave: kv = 64t + 32w + l31

    union U4 { uint4 q; unsigned short s[8]; };
    bf16x8 kc[4], kn[4];
    U4 va0, va1, vb0, vb1;

    // prologue: tile 0
    {
        const __hip_bfloat16* kr = Kg + (size_t)(32 * w + l31) * QKVD;
#pragma unroll
        for (int kd = 0; kd < 4; kd++)
            kc[kd] = *reinterpret_cast<const bf16x8*>(kr + kd * 16 + lg2 * 8);
        const __hip_bfloat16* vr = Vg + (size_t)(2 * kvp) * QKVD + 16 * dgrp;
        va0.q = *reinterpret_cast<const uint4*>(vr);
        va1.q = *reinterpret_cast<const uint4*>(vr + 8);
        vb0.q = *reinterpret_cast<const uint4*>(vr + QKVD);
        vb1.q = *reinterpret_cast<const uint4*>(vr + QKVD + 8);
    }
    // write V^T tile 0 (swizzled: chunk' = (kvp>>2) ^ (d&7), slot = kvp&3)
    {
        __hip_bfloat16* vt = VT;
#pragma unroll
        for (int i = 0; i < 16; i++) {
            int d = 16 * dgrp + i;
            unsigned short e0 = (i < 8) ? va0.s[i] : va1.s[i - 8];
            unsigned short e1 = (i < 8) ? vb0.s[i] : vb1.s[i - 8];
            *reinterpret_cast<ushort2*>(
                &vt[d * 64 + 8 * ((kvp >> 2) ^ (d & 7)) + 2 * (kvp & 3)]) = make_ushort2(e0, e1);
        }
    }
    __syncthreads();

    int buf = 0;
    for (int t = 0; t < T; t++) {
        bool hn = (t + 1 < T);
        if (hn) {  // prefetch tile t+1 (K->regs, V->regs)
            const __hip_bfloat16* kr = Kg + (size_t)(64 * (t + 1) + 32 * w + l31) * QKVD;
#pragma unroll
            for (int kd = 0; kd < 4; kd++)
                kn[kd] = *reinterpret_cast<const bf16x8*>(kr + kd * 16 + lg2 * 8);
            const __hip_bfloat16* vr = Vg + (size_t)(64 * (t + 1) + 2 * kvp) * QKVD + 16 * dgrp;
            va0.q = *reinterpret_cast<const uint4*>(vr);
            va1.q = *reinterpret_cast<const uint4*>(vr + 8);
            vb0.q = *reinterpret_cast<const uint4*>(vr + QKVD);
            vb1.q = *reinterpret_cast<const uint4*>(vr + QKVD + 8);
        }

        int kvbase = 64 * t + 32 * w;
        bool active = (kvbase <= q0 + 31);

        if (active) {
            // ---- S^T = mfma32(K, Q): col=q=l31, row=kv_local=(j&3)+8*(j>>2)+4*lg2 ----
            f32x16 st = {};
#pragma unroll
            for (int kd = 0; kd < 4; kd++)
                st = mfma32(kc[kd], qf[kd], st);

            // causal mask (only possible on final tile)
            if (t == T - 1) {
                int qg_ = q0 + l31;
#pragma unroll
                for (int j = 0; j < 16; j++) {
                    int kv = kvbase + (j & 3) + 8 * (j >> 2) + 4 * lg2;
                    if (kv > qg_) st[j] = -3.0e38f;
                }
            }
            // ---- online softmax (per-lane q=l31; halves merged via shfl 32) ----
            float tm[16];
#pragma unroll
            for (int j = 0; j < 16; j++) tm[j] = st[j];
#pragma unroll
            for (int dd = 8; dd >= 1; dd >>= 1)
#pragma unroll
                for (int j = 0; j < 8; j++)
                    if (j < dd) tm[j] = fmaxf(tm[j], tm[j + dd]);
            float mx = fmaxf(tm[0], __shfl_xor(tm[0], 32, 64));
            float mnew = fmaxf(m, mx);
            float sc = __builtin_amdgcn_exp2f((m - mnew) * KS2);
#pragma unroll
            for (int j = 0; j < 16; j++)
                st[j] = __builtin_amdgcn_exp2f((st[j] - mnew) * KS2);
            float ts[16];
#pragma unroll
            for (int j = 0; j < 16; j++) ts[j] = st[j];
#pragma unroll
            for (int dd = 8; dd >= 1; dd >>= 1)
#pragma unroll
                for (int j = 0; j < 8; j++)
                    if (j < dd) ts[j] += ts[j + dd];
            float ls = ts[0] + __shfl_xor(ts[0], 32, 64);
            l = l * sc + ls;
            m = mnew;
            o0 *= sc;
            o1 *= sc;

            // ---- in-register P repack: per ks, halves exchange 2 words via shfl_xor(32) ----
            __hip_bfloat16* vt = VT + buf * 4096;
#pragma unroll
            for (int ks = 0; ks < 2; ks++) {
                unsigned int a0 = pack_bf16(st[8 * ks + 0], st[8 * ks + 1]);
                unsigned int a1 = pack_bf16(st[8 * ks + 2], st[8 * ks + 3]);
                unsigned int b0 = pack_bf16(st[8 * ks + 4], st[8 * ks + 5]);
                unsigned int b1 = pack_bf16(st[8 * ks + 6], st[8 * ks + 7]);
                unsigned int pa0 = __shfl_xor(a0, 32, 64);
                unsigned int pa1 = __shfl_xor(a1, 32, 64);
                unsigned int pb0 = __shfl_xor(b0, 32, 64);
                unsigned int pb1 = __shfl_xor(b1, 32, 64);
                union { unsigned int u[4]; bf16x8 v; } pf;
                pf.u[0] = lg2 ? pb0 : a0;
                pf.u[1] = lg2 ? pb1 : a1;
                pf.u[2] = lg2 ? b0 : pa0;
                pf.u[3] = lg2 ? b1 : pa1;
                // ---- O^T += mfma32(V^T, P^T) ----
#pragma unroll
                for (int dh = 0; dh < 2; dh++) {
                    int d = dh * 32 + l31;
                    bf16x8 vf = *reinterpret_cast<const bf16x8*>(
                        &vt[d * 64 + 8 * ((4 * w + 2 * ks + lg2) ^ (l31 & 7))]);
                    if (dh == 0) o0 = mfma32(vf, pf.v, o0);
                    else         o1 = mfma32(vf, pf.v, o1);
                }
            }
        }

        if (hn) {  // write prefetched V^T into other buffer
            __hip_bfloat16* vt = VT + (buf ^ 1) * 4096;
#pragma unroll
            for (int i = 0; i < 16; i++) {
                int d = 16 * dgrp + i;
                unsigned short e0 = (i < 8) ? va0.s[i] : va1.s[i - 8];
                unsigned short e1 = (i < 8) ? vb0.s[i] : vb1.s[i - 8];
                *reinterpret_cast<ushort2*>(
                    &vt[d * 64 + 8 * ((kvp >> 2) ^ (d & 7)) + 2 * (kvp & 3)]) = make_ushort2(e0, e1);
            }
#pragma unroll
            for (int kd = 0; kd < 4; kd++) kc[kd] = kn[kd];
        }
        __syncthreads();
        buf ^= 1;
    }

    // ---- combine wave partials (O^T: col=q=l31, rows=d) ----
    if (w == 1) {
#pragma unroll
        for (int j = 0; j < 16; j++) {
            int dl = (j & 3) + 8 * (j >> 2) + 4 * lg2;
            SC[dl * 32 + l31] = o0[j];
            SC[(32 + dl) * 32 + l31] = o1[j];
        }
        if (lg2 == 0) {
            ML[l31] = m;
            ML[32 + l31] = l;
        }
    }
    __syncthreads();
    if (w == 0) {
        float mb = ML[l31];
        float lb = ML[32 + l31];
        float M = fmaxf(m, mb);
        float ea = __builtin_amdgcn_exp2f((m - M) * KS2);
        float eb = __builtin_amdgcn_exp2f((mb - M) * KS2);
        float L = l * ea + lb * eb;
        float linv = 1.0f / L;
#pragma unroll
        for (int od = 0; od < 2; od++) {
#pragma unroll
            for (int g = 0; g < 4; g++) {
                int dbase = od * 32 + 8 * g + 4 * lg2;
                ushort4 w4;
                float v0 = (od ? o1[4 * g + 0] : o0[4 * g + 0]) * ea + SC[(dbase + 0) * 32 + l31] * eb;
                float v1 = (od ? o1[4 * g + 1] : o0[4 * g + 1]) * ea + SC[(dbase + 1) * 32 + l31] * eb;
                float v2 = (od ? o1[4 * g + 2] : o0[4 * g + 2]) * ea + SC[(dbase + 2) * 32 + l31] * eb;
                float v3 = (od ? o1[4 * g + 3] : o0[4 * g + 3]) * ea + SC[(dbase + 3) * 32 + l31] * eb;
                w4.x = f2bf_bits(v0 * linv);
                w4.y = f2bf_bits(v1 * linv);
                w4.z = f2bf_bits(v2 * linv);
                w4.w = f2bf_bits(v3 * linv);
                *reinterpret_cast<ushort4*>(&OL[l31 * 72 + dbase]) = w4;
            }
        }
    }
    __syncthreads();
    // coalesced store: 128 threads cover 32 q-rows x 64 d
    {
        int r = tid >> 2, c = (tid & 3) * 16;
        __hip_bfloat16* dst = attn_out + (size_t)(bbase + q0 + r) * DMODEL + h * HDIM + c;
        *reinterpret_cast<uint4*>(dst) = *reinterpret_cast<const uint4*>(&OL[r * 72 + c]);
        *reinterpret_cast<uint4*>(dst + 8) = *reinterpret_cast<const uint4*>(&OL[r * 72 + c + 8]);
    }
}

// ---------------- launch ----------------

extern "C" void kernel_launch(void* const* d_in, const int* in_sizes, int n_in,
                              void* d_out, int out_size, void* d_ws, size_t ws_size,
                              hipStream_t stream) {
    const float* hidden = (const float*)d_in[0];   // [2,2048,768]
    const float* w_attn = (const float*)d_in[1];   // [768,2304]
    const float* b_attn = (const float*)d_in[2];   // [2304]
    const float* w_proj = (const float*)d_in[3];   // [768,768]
    const float* b_proj = (const float*)d_in[4];   // [768]
    float* out = (float*)d_out;                    // [2,2048,768]

    char* ws = (char*)d_ws;
    __hip_bfloat16* Xb  = (__hip_bfloat16*)(ws + 0);         // 4096*768*2
    __hip_bfloat16* Wta = (__hip_bfloat16*)(ws + 6291456);   // 2304*768*2
    __hip_bfloat16* Wtp = (__hip_bfloat16*)(ws + 9830400);   // 768*768*2
    __hip_bfloat16* QKV = (__hip_bfloat16*)(ws + 11010048);  // 4096*2304*2
    __hip_bfloat16* AO  = (__hip_bfloat16*)(ws + 29884416);  // 4096*768*2

    const int M = BATCH * SEQ;  // 4096

    f32_to_bf16_k<<<dim3(M * DMODEL / (256 * 4)), dim3(256), 0, stream>>>(hidden, Xb);
    transpose_f32_to_bf16<<<dim3(QKVD / 32, DMODEL / 32), dim3(256), 0, stream>>>(w_attn, Wta, DMODEL, QKVD);
    transpose_f32_to_bf16<<<dim3(DMODEL / 32, DMODEL / 32), dim3(256), 0, stream>>>(w_proj, Wtp, DMODEL, DMODEL);
    gemm_bt<true><<<dim3(QKVD / 128, M / 128), dim3(256), 0, stream>>>(Xb, Wta, b_attn, QKV, M, QKVD, DMODEL);
    flash_attn<<<dim3(1536), dim3(128), 0, stream>>>(QKV, AO);
    gemm_bt<false><<<dim3(DMODEL / 128, M / 128), dim3(256), 0, stream>>>(AO, Wtp, b_proj, out, M, DMODEL, DMODEL);
}